// Round 8
// baseline (432.102 us; speedup 1.0000x reference)
//
#include <hip/hip_runtime.h>
#include <hip/hip_bf16.h>
#include <stdint.h>

// MutualCrossAttention: B=8, C=64, H=W=64 -> T=4096 tokens. Inputs FP32, output FP32.
// dir A: Q=x1, K=V=x2 ; dir B: Q=x2, K=V=x1 ; out = outA + outB, layout [b][c][t].
// R20 = R18 VERBATIM (frag-packed K/V/Q, K ping-pong + V named-reg prefetch, 1
// pacing barrier/j — best measured: 120us attn) with the OCCUPANCY DECLARATION
// fixed. Evidence across R12-R19: resident blocks/CU tracked the launch-bounds
// waves-per-EU arg, NOT the resource fit (all (512,4) kernels ran 44% occupancy,
// all (512,2) kernels ran 22%, at VGPR 64..108 and LDS 37.9..74.8KB which always
// fit 2 blocks). R18's stall-dominated per-wave chains need the 2nd block's TLP.
// amdgpu_waves_per_eu(4,4): min=4 -> CP targets 2 blocks/CU; max=4 -> allocator
// budget = 512/4 = 128 VGPR >= R18's 108, so no R14-style spill (that came from
// min=4 with unbounded max -> allocator chose the 64-reg tier and spilled).
//   kt chunk(tt,mt,ch):  lane(quad,l16) holds K[t=tt*64+mt*16+l16][c=ch*32+quad*8+e]
//   vt chunk(tt,ch2,ct): lane(quad,l16) holds V[c=ct*16+l16][t=tt*64+ch2*32+quad*8+e]
// Q frags are kt chunks at (qt, mt=pair*2+rb, ch) — all hot loads contiguous 1KB.
//   - S^T composition (A=K,B=Q then A=V,B=P^T) proved in R3-R5; P^T C/D layout
//     gives 4 consecutive tokens/lane -> b64 pbuf write, b128 read, stride-72.
//   - lp is one scalar per lane (q = l16 column), butterflied over quads.
//   - O^T epilogue: row=c, col=q -> scalar f32 stores coalesced over l16.
// ws: [0,8MB) kt bf16 frag-packed {x1,x2} PRE-SCALED by sqrt(log2(e)/8);
//     [8MB,16MB) vt bf16 frag-packed {x1,x2} unscaled.

#define TT 4096
#define CC 64
#define NB 8

typedef float f32x4 __attribute__((ext_vector_type(4)));
typedef float f32x4a __attribute__((ext_vector_type(4), may_alias));
typedef short s16x8 __attribute__((ext_vector_type(8)));
typedef unsigned int u32x2a __attribute__((ext_vector_type(2), may_alias));
typedef unsigned int u32x4a __attribute__((ext_vector_type(4), may_alias));
typedef float f32a __attribute__((may_alias));

static __device__ __forceinline__ unsigned fbits(float x) { return __float_as_uint(x); }
static __device__ __forceinline__ ushort bf16of(float v) {
    return (ushort)((fbits(v) + 0x8000u) >> 16);
}
static __device__ __forceinline__ unsigned pack2(float a, float b) {
    return __builtin_amdgcn_perm(fbits(b) + 0x8000u, fbits(a) + 0x8000u, 0x07060302u);
}
static __device__ __forceinline__ s16x8 load_frag(const void* p) {
    u32x4a t = *(const u32x4a*)p;
    return __builtin_bit_cast(s16x8, t);
}

#define SQC1 0.4246609177f  // sqrt(log2(e)/8), applied to kt on both Q and K sides

// grid (TT/64, NB, 2), 256 threads. Reads c-major f32, emits frag-packed bf16.
__global__ void prep_k(const float* __restrict__ x1, const float* __restrict__ x2,
                       ushort* __restrict__ kt, ushort* __restrict__ vt) {
    const int inp = blockIdx.z, b = blockIdx.y, tt = blockIdx.x;
    const float* src = (inp == 0 ? x1 : x2) + (size_t)b * CC * TT;
    const size_t plane = (size_t)TT * CC;
    ushort* kd = kt + (size_t)(inp * NB + b) * plane;
    ushort* vd = vt + (size_t)(inp * NB + b) * plane;
    __shared__ ushort lds[64][72];
    const int tid = threadIdx.x;
    const int c  = tid >> 2;        // 0..63: channel row
    const int tg = tid & 3;         // 16-token group within the 64-token tile
    const float* srow = src + (size_t)c * TT + tt * 64 + tg * 16;
    unsigned hw[8];
#pragma unroll
    for (int i = 0; i < 4; ++i) {
        f32x4a v = *(const f32x4a*)(srow + i * 4);
        hw[2 * i]     = pack2(v[0], v[1]);
        hw[2 * i + 1] = pack2(v[2], v[3]);
#pragma unroll
        for (int k = 0; k < 4; ++k) lds[tg * 16 + i * 4 + k][c] = bf16of(v[k] * SQC1);
    }
    // vt frag-packed (unscaled): thread(c,tg) owns V[c][t_local=tg*16..+16] =
    // chunk(tt, ch2=tg>>1, ct=c>>4), lanes (quad=(tg&1)*2 and +1, l16=c&15).
    {
        ushort* vchunk = vd + (((size_t)tt * 2 + (tg >> 1)) * 4 + (c >> 4)) * 512;
        const int l16v = c & 15;
        const int q0v  = (tg & 1) * 2;
        u32x4a w0 = {hw[0], hw[1], hw[2], hw[3]};
        u32x4a w1 = {hw[4], hw[5], hw[6], hw[7]};
        *(u32x4a*)(vchunk + (size_t)(q0v * 16 + l16v) * 8)       = w0;
        *(u32x4a*)(vchunk + (size_t)((q0v + 1) * 16 + l16v) * 8) = w1;
    }
    __syncthreads();
    // kt frag-packed (scaled, from transposed LDS): tid = mt*64 + quad*16 + l16.
    // chunk(tt, mt, ch): lane holds 8 consecutive c at row t = mt*16 + l16.
    const int mt   = tid >> 6;
    const int quad = (tid >> 4) & 3;
    const int l16  = tid & 15;
    const int t    = mt * 16 + l16;
#pragma unroll
    for (int ch = 0; ch < 2; ++ch) {
        u32x4a w = *(const u32x4a*)&lds[t][ch * 32 + quad * 8];
        *(u32x4a*)(kd + (((size_t)tt * 4 + mt) * 2 + ch) * 512 +
                   (size_t)(quad * 16 + l16) * 8) = w;
    }
}

// grid = 512 blocks (qt 0..63 x b 0..7), 512 threads = 8 waves.
// wave: dir = w&1, pair = (w>>1)&1, ks = w>>2 (2048-token half).
__global__ __attribute__((amdgpu_flat_work_group_size(512, 512),
                          amdgpu_waves_per_eu(4, 4)))
void attn_fused_k(const ushort* __restrict__ kt, const ushort* __restrict__ vt,
                  float* __restrict__ out) {
    const int b    = blockIdx.x & 7;
    const int qt   = blockIdx.x >> 3;
    const int tid  = threadIdx.x;
    const int wave = tid >> 6;
    const int lane = tid & 63;
    const int quad = lane >> 4;
    const int l16  = lane & 15;
    const int dir  = wave & 1;
    const int pair = (wave >> 1) & 1;
    const int ks   = wave >> 2;
    const int q0   = qt * 64 + pair * 32;

    const size_t plane = (size_t)TT * CC;
    // All hot-loop loads: base + chunk*512 + lane*8 (ushorts) = contiguous 1KB/instr.
    const ushort* Qp = kt + (size_t)((dir == 0 ? 0 : NB) + b) * plane + (size_t)lane * 8;
    const ushort* Kp = kt + (size_t)((dir == 0 ? NB : 0) + b) * plane + (size_t)lane * 8;
    const ushort* Vp = vt + (size_t)((dir == 0 ? NB : 0) + b) * plane + (size_t)lane * 8;

    __shared__ __align__(16) ushort pbuf[8][2][16][72];    // 36.9 KB (q rows, tok cols)
    __shared__ float lpx[8][2][16];                        // 1 KB
    f32a* xbuf = (f32a*)&pbuf[0][0][0][0];                 // 16 KB overlay, post-loop

    // Q b-frags = kt chunks (qt, mt = pair*2 + rb, ch), pre-scaled.
    s16x8 qf[2][2];
#pragma unroll
    for (int rb = 0; rb < 2; ++rb)
#pragma unroll
        for (int ch = 0; ch < 2; ++ch)
            qf[rb][ch] = load_frag(Qp + (((size_t)qt * 4 + pair * 2 + rb) * 2 + ch) * 512);

    f32x4 accO[2][4];  // O^T partial: row=c=quad*4+r (+ct*16), col=q=l16 (+rb*16)
#pragma unroll
    for (int rb = 0; rb < 2; ++rb)
#pragma unroll
        for (int ct = 0; ct < 4; ++ct) accO[rb][ct] = (f32x4){0.f, 0.f, 0.f, 0.f};
    float lp[2] = {0.f, 0.f};

    // Named registers only (R14/R15 lesson: arrays spill under pressure).
    s16x8 kA0, kA1, kA2, kA3, kA4, kA5, kA6, kA7;   // K set A: chunks (mt,ch)
    s16x8 kB0, kB1, kB2, kB3, kB4, kB5, kB6, kB7;   // K set B
    s16x8 v0, v1, v2, v3, v4, v5, v6, v7;           // V: (ch2,ct)

    auto loadKA = [&](int j) {
        const ushort* p = Kp + (size_t)(ks * 32 + j) * 4096;
        kA0 = load_frag(p);          kA1 = load_frag(p + 512);
        kA2 = load_frag(p + 1024);   kA3 = load_frag(p + 1536);
        kA4 = load_frag(p + 2048);   kA5 = load_frag(p + 2560);
        kA6 = load_frag(p + 3072);   kA7 = load_frag(p + 3584);
    };
    auto loadKB = [&](int j) {
        const ushort* p = Kp + (size_t)(ks * 32 + j) * 4096;
        kB0 = load_frag(p);          kB1 = load_frag(p + 512);
        kB2 = load_frag(p + 1024);   kB3 = load_frag(p + 1536);
        kB4 = load_frag(p + 2048);   kB5 = load_frag(p + 2560);
        kB6 = load_frag(p + 3072);   kB7 = load_frag(p + 3584);
    };
    auto loadV = [&](int j) {
        const ushort* p = Vp + (size_t)(ks * 32 + j) * 4096;
        v0 = load_frag(p);           v1 = load_frag(p + 512);
        v2 = load_frag(p + 1024);    v3 = load_frag(p + 1536);
        v4 = load_frag(p + 2048);    v5 = load_frag(p + 2560);
        v6 = load_frag(p + 3072);    v7 = load_frag(p + 3584);
    };

    // One mt-slice of S^T: D[row=tok=quad*4+r (+mt*16)][col=q=l16] -> b64 P write.
    auto SmT = [&](s16x8 kc0, s16x8 kc1, int mt) {
#pragma unroll
        for (int rb = 0; rb < 2; ++rb) {
            f32x4 s = (f32x4){0.f, 0.f, 0.f, 0.f};
            s = __builtin_amdgcn_mfma_f32_16x16x32_bf16(kc0, qf[rb][0], s, 0, 0, 0);
            s = __builtin_amdgcn_mfma_f32_16x16x32_bf16(kc1, qf[rb][1], s, 0, 0, 0);
            float p0 = __builtin_amdgcn_exp2f(s[0]);
            float p1 = __builtin_amdgcn_exp2f(s[1]);
            float p2 = __builtin_amdgcn_exp2f(s[2]);
            float p3 = __builtin_amdgcn_exp2f(s[3]);
            lp[rb] += (p0 + p1) + (p2 + p3);
            u32x2a w;
            w[0] = pack2(p0, p1);
            w[1] = pack2(p2, p3);
            *(u32x2a*)&pbuf[wave][rb][l16][mt * 16 + quad * 4] = w;
        }
    };
    // PV(j): A = V (prefetched named regs) [m=c=l16(+ct*16)][k=tok],
    //        B = P^T [n=q=l16][k=tok] (b128 LDS read). Pure reg-MFMA otherwise.
    auto PVphase = [&]() {
        s16x8 pf0a = load_frag(&pbuf[wave][0][l16][quad * 8]);
        s16x8 pf1a = load_frag(&pbuf[wave][1][l16][quad * 8]);
        accO[0][0] = __builtin_amdgcn_mfma_f32_16x16x32_bf16(v0, pf0a, accO[0][0], 0, 0, 0);
        accO[1][0] = __builtin_amdgcn_mfma_f32_16x16x32_bf16(v0, pf1a, accO[1][0], 0, 0, 0);
        accO[0][1] = __builtin_amdgcn_mfma_f32_16x16x32_bf16(v1, pf0a, accO[0][1], 0, 0, 0);
        accO[1][1] = __builtin_amdgcn_mfma_f32_16x16x32_bf16(v1, pf1a, accO[1][1], 0, 0, 0);
        accO[0][2] = __builtin_amdgcn_mfma_f32_16x16x32_bf16(v2, pf0a, accO[0][2], 0, 0, 0);
        accO[1][2] = __builtin_amdgcn_mfma_f32_16x16x32_bf16(v2, pf1a, accO[1][2], 0, 0, 0);
        accO[0][3] = __builtin_amdgcn_mfma_f32_16x16x32_bf16(v3, pf0a, accO[0][3], 0, 0, 0);
        accO[1][3] = __builtin_amdgcn_mfma_f32_16x16x32_bf16(v3, pf1a, accO[1][3], 0, 0, 0);
        s16x8 pf0b = load_frag(&pbuf[wave][0][l16][32 + quad * 8]);
        s16x8 pf1b = load_frag(&pbuf[wave][1][l16][32 + quad * 8]);
        accO[0][0] = __builtin_amdgcn_mfma_f32_16x16x32_bf16(v4, pf0b, accO[0][0], 0, 0, 0);
        accO[1][0] = __builtin_amdgcn_mfma_f32_16x16x32_bf16(v4, pf1b, accO[1][0], 0, 0, 0);
        accO[0][1] = __builtin_amdgcn_mfma_f32_16x16x32_bf16(v5, pf0b, accO[0][1], 0, 0, 0);
        accO[1][1] = __builtin_amdgcn_mfma_f32_16x16x32_bf16(v5, pf1b, accO[1][1], 0, 0, 0);
        accO[0][2] = __builtin_amdgcn_mfma_f32_16x16x32_bf16(v6, pf0b, accO[0][2], 0, 0, 0);
        accO[1][2] = __builtin_amdgcn_mfma_f32_16x16x32_bf16(v6, pf1b, accO[1][2], 0, 0, 0);
        accO[0][3] = __builtin_amdgcn_mfma_f32_16x16x32_bf16(v7, pf0b, accO[0][3], 0, 0, 0);
        accO[1][3] = __builtin_amdgcn_mfma_f32_16x16x32_bf16(v7, pf1b, accO[1][3], 0, 0, 0);
    };

    // Ping-pong pipeline, unroll 2. Per j: [pacing bar] -> issue next K set ->
    // S(j) (waits only the OLDER K set via counted vmcnt) -> PV(j) -> issue V(j+1)
    // (WAR-safe: PV already consumed v*). Each prefetch gets a full S+PV of cover.
    loadKA(0);
    loadV(0);
#pragma unroll 1
    for (int j = 0; j < 32; j += 2) {
        __syncthreads();                 // pacing: keep pair-waves L1-coherent
        loadKB(j + 1);
        SmT(kA0, kA1, 0); SmT(kA2, kA3, 1); SmT(kA4, kA5, 2); SmT(kA6, kA7, 3);
        PVphase();                       // PV(j)
        loadV(j + 1);
        __syncthreads();
        if (j + 2 < 32) loadKA(j + 2);
        SmT(kB0, kB1, 0); SmT(kB2, kB3, 1); SmT(kB4, kB5, 2); SmT(kB6, kB7, 3);
        PVphase();                       // PV(j+1)
        if (j + 2 < 32) loadV(j + 2);
    }

    // Denominator: quads hold disjoint token subsets for col q=l16.
    float inv[2];
#pragma unroll
    for (int rb = 0; rb < 2; ++rb) {
        float l = lp[rb];
        l += __shfl_xor(l, 16);
        l += __shfl_xor(l, 32);
        lp[rb] = l;
        if (lane < 16) lpx[wave][rb][l16] = l;
    }
    __syncthreads();  // all waves done with pbuf -> xbuf overlay safe; lpx visible
#pragma unroll
    for (int rb = 0; rb < 2; ++rb)
        inv[rb] = __builtin_amdgcn_rcpf(lp[rb] + lpx[wave ^ 4][rb][l16]);

    // 4-phase merge over g = (ks,dir) into xbuf[pair]; g==0 stores.
    const int g = (ks << 1) | dir;
#pragma unroll 1
    for (int ph = 3; ph >= 1; --ph) {
        if (g == ph) {
#pragma unroll
            for (int rb = 0; rb < 2; ++rb)
#pragma unroll
                for (int ct = 0; ct < 4; ++ct)
#pragma unroll
                    for (int r = 0; r < 4; ++r) {
                        const int slot = (pair * 32 + rb * 16 + ct * 4 + r) * 64 + lane;
                        float v = accO[rb][ct][r] * inv[rb];
                        if (ph == 3) xbuf[slot] = v;
                        else xbuf[slot] += v;
                    }
        }
        __syncthreads();
    }
    if (g == 0) {
        float* ob = out + (size_t)b * plane;
#pragma unroll
        for (int rb = 0; rb < 2; ++rb)
#pragma unroll
            for (int ct = 0; ct < 4; ++ct)
#pragma unroll
                for (int r = 0; r < 4; ++r) {
                    float v = accO[rb][ct][r] * inv[rb] +
                              xbuf[(pair * 32 + rb * 16 + ct * 4 + r) * 64 + lane];
                    // out[c = ct*16+quad*4+r][t = q0+rb*16+l16]: coalesced over l16
                    ob[(size_t)(ct * 16 + quad * 4 + r) * TT + q0 + rb * 16 + l16] = v;
                }
    }
}

extern "C" void kernel_launch(void* const* d_in, const int* in_sizes, int n_in,
                              void* d_out, int out_size, void* d_ws, size_t ws_size,
                              hipStream_t stream) {
    const float* x1 = (const float*)d_in[0];
    const float* x2 = (const float*)d_in[1];
    ushort* kt = (ushort*)d_ws;                              // 8 MB frag-packed K/Q
    ushort* vt = (ushort*)d_ws + (size_t)2 * NB * TT * CC;   // 8 MB frag-packed V

    hipLaunchKernelGGL(prep_k, dim3(TT / 64, NB, 2), dim3(256), 0, stream, x1, x2, kt, vt);
    hipLaunchKernelGGL(attn_fused_k, dim3(64 * NB), dim3(512), 0, stream,
                       kt, vt, (float*)d_out);
}

// Round 9
// 180.086 us; speedup vs baseline: 2.3994x; 2.3994x over previous
//
#include <hip/hip_runtime.h>
#include <hip/hip_bf16.h>
#include <stdint.h>

// MutualCrossAttention: B=8, C=64, H=W=64 -> T=4096 tokens. Inputs FP32, output FP32.
// dir A: Q=x1, K=V=x2 ; dir B: Q=x2, K=V=x1 ; out = outA + outB, layout [b][c][t].
// R21 = R19's kernel (frag-packed K/V/Q; single-K named-reg prefetch covered by
// PV; in-phase V loads) RE-BLOCKED AT 256 THREADS to fix residency granularity.
// Register law pinned by R12-R20: MFMA kernels get ~256 VGPR/SIMD (AGPR-split
// file); waves/SIMD = floor(256/VGPR); allocator budget = 256/min_waves_per_eu.
// A 512-thr block occupies 2 waves on EVERY SIMD -> co-residency needs VGPR<=64
// (spill-impossible for this pipeline, proved R14/R20). A 256-thr block is
// 1 wave/SIMD -> at VGPR<=85 THREE blocks co-reside = 12 waves/CU, +50% TLP
// over R18's 8. R19 (VGPR 80, same inner code) lost to R18 only on TLP; this
// gives it the TLP. launch_bounds(256,3): budget 256/3=85 >= R19's measured 80.
// Block = (b, qt, pair); 4 waves = (dir, ks); merge over g=(ks,dir) in-block
// (pair's xbuf slots were already disjoint -> pair splits to blockIdx freely).
//   kt chunk(tt,mt,ch):  lane(quad,l16) holds K[t=tt*64+mt*16+l16][c=ch*32+quad*8+e]
//   vt chunk(tt,ch2,ct): lane(quad,l16) holds V[c=ct*16+l16][t=tt*64+ch2*32+quad*8+e]
// Q frags are kt chunks at (qt, mt=pair*2+rb, ch) — all hot loads contiguous 1KB.
//   - S^T composition (A=K,B=Q then A=V,B=P^T): P^T C/D layout gives 4
//     consecutive tokens/lane -> b64 pbuf write, b128 read, stride-72.
//   - lp is one scalar per lane (q = l16 column), butterflied over quads;
//     ks-partner wave = wave^2 via lpx.
//   - O^T epilogue: row=c, col=q -> scalar f32 stores coalesced over l16.
// ws: [0,8MB) kt bf16 frag-packed {x1,x2} PRE-SCALED by sqrt(log2(e)/8);
//     [8MB,16MB) vt bf16 frag-packed {x1,x2} unscaled.

#define TT 4096
#define CC 64
#define NB 8

typedef float f32x4 __attribute__((ext_vector_type(4)));
typedef float f32x4a __attribute__((ext_vector_type(4), may_alias));
typedef short s16x8 __attribute__((ext_vector_type(8)));
typedef unsigned int u32x2a __attribute__((ext_vector_type(2), may_alias));
typedef unsigned int u32x4a __attribute__((ext_vector_type(4), may_alias));
typedef float f32a __attribute__((may_alias));

static __device__ __forceinline__ unsigned fbits(float x) { return __float_as_uint(x); }
static __device__ __forceinline__ ushort bf16of(float v) {
    return (ushort)((fbits(v) + 0x8000u) >> 16);
}
static __device__ __forceinline__ unsigned pack2(float a, float b) {
    return __builtin_amdgcn_perm(fbits(b) + 0x8000u, fbits(a) + 0x8000u, 0x07060302u);
}
static __device__ __forceinline__ s16x8 load_frag(const void* p) {
    u32x4a t = *(const u32x4a*)p;
    return __builtin_bit_cast(s16x8, t);
}

#define SQC1 0.4246609177f  // sqrt(log2(e)/8), applied to kt on both Q and K sides

// grid (TT/64, NB, 2), 256 threads. Reads c-major f32, emits frag-packed bf16.
__global__ void prep_k(const float* __restrict__ x1, const float* __restrict__ x2,
                       ushort* __restrict__ kt, ushort* __restrict__ vt) {
    const int inp = blockIdx.z, b = blockIdx.y, tt = blockIdx.x;
    const float* src = (inp == 0 ? x1 : x2) + (size_t)b * CC * TT;
    const size_t plane = (size_t)TT * CC;
    ushort* kd = kt + (size_t)(inp * NB + b) * plane;
    ushort* vd = vt + (size_t)(inp * NB + b) * plane;
    __shared__ ushort lds[64][72];
    const int tid = threadIdx.x;
    const int c  = tid >> 2;        // 0..63: channel row
    const int tg = tid & 3;         // 16-token group within the 64-token tile
    const float* srow = src + (size_t)c * TT + tt * 64 + tg * 16;
    unsigned hw[8];
#pragma unroll
    for (int i = 0; i < 4; ++i) {
        f32x4a v = *(const f32x4a*)(srow + i * 4);
        hw[2 * i]     = pack2(v[0], v[1]);
        hw[2 * i + 1] = pack2(v[2], v[3]);
#pragma unroll
        for (int k = 0; k < 4; ++k) lds[tg * 16 + i * 4 + k][c] = bf16of(v[k] * SQC1);
    }
    // vt frag-packed (unscaled): thread(c,tg) owns V[c][t_local=tg*16..+16] =
    // chunk(tt, ch2=tg>>1, ct=c>>4), lanes (quad=(tg&1)*2 and +1, l16=c&15).
    {
        ushort* vchunk = vd + (((size_t)tt * 2 + (tg >> 1)) * 4 + (c >> 4)) * 512;
        const int l16v = c & 15;
        const int q0v  = (tg & 1) * 2;
        u32x4a w0 = {hw[0], hw[1], hw[2], hw[3]};
        u32x4a w1 = {hw[4], hw[5], hw[6], hw[7]};
        *(u32x4a*)(vchunk + (size_t)(q0v * 16 + l16v) * 8)       = w0;
        *(u32x4a*)(vchunk + (size_t)((q0v + 1) * 16 + l16v) * 8) = w1;
    }
    __syncthreads();
    // kt frag-packed (scaled, from transposed LDS): tid = mt*64 + quad*16 + l16.
    // chunk(tt, mt, ch): lane holds 8 consecutive c at row t = mt*16 + l16.
    const int mt   = tid >> 6;
    const int quad = (tid >> 4) & 3;
    const int l16  = tid & 15;
    const int t    = mt * 16 + l16;
#pragma unroll
    for (int ch = 0; ch < 2; ++ch) {
        u32x4a w = *(const u32x4a*)&lds[t][ch * 32 + quad * 8];
        *(u32x4a*)(kd + (((size_t)tt * 4 + mt) * 2 + ch) * 512 +
                   (size_t)(quad * 16 + l16) * 8) = w;
    }
}

// grid = 1024 blocks (qt 0..63 x pair 0..1 x b 0..7), 256 threads = 4 waves.
// wave: dir = w&1, ks = w>>1 (2048-token half). b in low bits -> XCD spread.
__global__ __launch_bounds__(256, 3)
void attn_fused_k(const ushort* __restrict__ kt, const ushort* __restrict__ vt,
                  float* __restrict__ out) {
    const int b    = blockIdx.x & 7;
    const int pair = (blockIdx.x >> 3) & 1;
    const int qt   = blockIdx.x >> 4;
    const int tid  = threadIdx.x;
    const int wave = tid >> 6;
    const int lane = tid & 63;
    const int quad = lane >> 4;
    const int l16  = lane & 15;
    const int dir  = wave & 1;
    const int ks   = wave >> 1;
    const int q0   = qt * 64 + pair * 32;

    const size_t plane = (size_t)TT * CC;
    // All hot-loop loads: base + chunk*512 + lane*8 (ushorts) = contiguous 1KB/instr.
    const ushort* Qp = kt + (size_t)((dir == 0 ? 0 : NB) + b) * plane + (size_t)lane * 8;
    const ushort* Kp = kt + (size_t)((dir == 0 ? NB : 0) + b) * plane + (size_t)lane * 8;
    const ushort* Vp = vt + (size_t)((dir == 0 ? NB : 0) + b) * plane + (size_t)lane * 8;

    __shared__ __align__(16) ushort pbuf[4][2][16][72];    // 18.4 KB (q rows, tok cols)
    __shared__ float lpx[4][2][16];                        // 0.5 KB
    f32a* xbuf = (f32a*)&pbuf[0][0][0][0];                 // 8 KB overlay, post-loop

    // Q b-frags = kt chunks (qt, mt = pair*2 + rb, ch), pre-scaled.
    s16x8 qf[2][2];
#pragma unroll
    for (int rb = 0; rb < 2; ++rb)
#pragma unroll
        for (int ch = 0; ch < 2; ++ch)
            qf[rb][ch] = load_frag(Qp + (((size_t)qt * 4 + pair * 2 + rb) * 2 + ch) * 512);

    f32x4 accO[2][4];  // O^T partial: row=c=quad*4+r (+ct*16), col=q=l16 (+rb*16)
#pragma unroll
    for (int rb = 0; rb < 2; ++rb)
#pragma unroll
        for (int ct = 0; ct < 4; ++ct) accO[rb][ct] = (f32x4){0.f, 0.f, 0.f, 0.f};
    float lp[2] = {0.f, 0.f};

    // K frags: SINGLE named prefetch set (arrays spill — R14/R15 lesson).
    s16x8 kA0, kA1, kA2, kA3, kA4, kA5, kA6, kA7;   // K chunks (mt,ch)

    auto loadK = [&](int j) {
        const ushort* p = Kp + (size_t)(ks * 32 + j) * 4096;
        kA0 = load_frag(p);          kA1 = load_frag(p + 512);
        kA2 = load_frag(p + 1024);   kA3 = load_frag(p + 1536);
        kA4 = load_frag(p + 2048);   kA5 = load_frag(p + 2560);
        kA6 = load_frag(p + 3072);   kA7 = load_frag(p + 3584);
    };

    // One mt-slice of S^T: D[row=tok=quad*4+r (+mt*16)][col=q=l16] -> b64 P write.
    auto SmT = [&](s16x8 kc0, s16x8 kc1, int mt) {
#pragma unroll
        for (int rb = 0; rb < 2; ++rb) {
            f32x4 s = (f32x4){0.f, 0.f, 0.f, 0.f};
            s = __builtin_amdgcn_mfma_f32_16x16x32_bf16(kc0, qf[rb][0], s, 0, 0, 0);
            s = __builtin_amdgcn_mfma_f32_16x16x32_bf16(kc1, qf[rb][1], s, 0, 0, 0);
            float p0 = __builtin_amdgcn_exp2f(s[0]);
            float p1 = __builtin_amdgcn_exp2f(s[1]);
            float p2 = __builtin_amdgcn_exp2f(s[2]);
            float p3 = __builtin_amdgcn_exp2f(s[3]);
            lp[rb] += (p0 + p1) + (p2 + p3);
            u32x2a w;
            w[0] = pack2(p0, p1);
            w[1] = pack2(p2, p3);
            *(u32x2a*)&pbuf[wave][rb][l16][mt * 16 + quad * 4] = w;
        }
    };
    // PV(j): A = V loaded IN-PHASE (transient regs, coalesced 1KB chunks; 12
    // waves/CU of TLP cover the L2 latency) [m=c=l16(+ct*16)][k=tok],
    //        B = P^T [n=q=l16][k=tok] (b128 LDS read).
    auto PVphase = [&](int j) {
        const ushort* p = Vp + (size_t)(ks * 32 + j) * 4096;
        s16x8 v0 = load_frag(p);           s16x8 v1 = load_frag(p + 512);
        s16x8 v2 = load_frag(p + 1024);    s16x8 v3 = load_frag(p + 1536);
        s16x8 v4 = load_frag(p + 2048);    s16x8 v5 = load_frag(p + 2560);
        s16x8 v6 = load_frag(p + 3072);    s16x8 v7 = load_frag(p + 3584);
        s16x8 pf0a = load_frag(&pbuf[wave][0][l16][quad * 8]);
        s16x8 pf1a = load_frag(&pbuf[wave][1][l16][quad * 8]);
        accO[0][0] = __builtin_amdgcn_mfma_f32_16x16x32_bf16(v0, pf0a, accO[0][0], 0, 0, 0);
        accO[1][0] = __builtin_amdgcn_mfma_f32_16x16x32_bf16(v0, pf1a, accO[1][0], 0, 0, 0);
        accO[0][1] = __builtin_amdgcn_mfma_f32_16x16x32_bf16(v1, pf0a, accO[0][1], 0, 0, 0);
        accO[1][1] = __builtin_amdgcn_mfma_f32_16x16x32_bf16(v1, pf1a, accO[1][1], 0, 0, 0);
        accO[0][2] = __builtin_amdgcn_mfma_f32_16x16x32_bf16(v2, pf0a, accO[0][2], 0, 0, 0);
        accO[1][2] = __builtin_amdgcn_mfma_f32_16x16x32_bf16(v2, pf1a, accO[1][2], 0, 0, 0);
        accO[0][3] = __builtin_amdgcn_mfma_f32_16x16x32_bf16(v3, pf0a, accO[0][3], 0, 0, 0);
        accO[1][3] = __builtin_amdgcn_mfma_f32_16x16x32_bf16(v3, pf1a, accO[1][3], 0, 0, 0);
        s16x8 pf0b = load_frag(&pbuf[wave][0][l16][32 + quad * 8]);
        s16x8 pf1b = load_frag(&pbuf[wave][1][l16][32 + quad * 8]);
        accO[0][0] = __builtin_amdgcn_mfma_f32_16x16x32_bf16(v4, pf0b, accO[0][0], 0, 0, 0);
        accO[1][0] = __builtin_amdgcn_mfma_f32_16x16x32_bf16(v4, pf1b, accO[1][0], 0, 0, 0);
        accO[0][1] = __builtin_amdgcn_mfma_f32_16x16x32_bf16(v5, pf0b, accO[0][1], 0, 0, 0);
        accO[1][1] = __builtin_amdgcn_mfma_f32_16x16x32_bf16(v5, pf1b, accO[1][1], 0, 0, 0);
        accO[0][2] = __builtin_amdgcn_mfma_f32_16x16x32_bf16(v6, pf0b, accO[0][2], 0, 0, 0);
        accO[1][2] = __builtin_amdgcn_mfma_f32_16x16x32_bf16(v6, pf1b, accO[1][2], 0, 0, 0);
        accO[0][3] = __builtin_amdgcn_mfma_f32_16x16x32_bf16(v7, pf0b, accO[0][3], 0, 0, 0);
        accO[1][3] = __builtin_amdgcn_mfma_f32_16x16x32_bf16(v7, pf1b, accO[1][3], 0, 0, 0);
    };

    // Per j: [pacing bar] -> S(j) (uses kA) -> issue K(j+1) (covered by PV(j))
    // -> PV(j) (in-phase V). pbuf is wave-private; barrier syncs only 4 waves.
    loadK(0);
#pragma unroll 1
    for (int j = 0; j < 32; ++j) {
        __syncthreads();                 // pacing: keep block's waves L1-coherent
        SmT(kA0, kA1, 0); SmT(kA2, kA3, 1); SmT(kA4, kA5, 2); SmT(kA6, kA7, 3);
        if (j < 31) loadK(j + 1);        // WAR-safe: S(j) already consumed kA
        PVphase(j);
    }

    // Denominator: quads hold disjoint token subsets for col q=l16; ks-partner
    // wave = wave^2 (bit1 = ks, bit0 = dir preserved).
    float inv[2];
#pragma unroll
    for (int rb = 0; rb < 2; ++rb) {
        float l = lp[rb];
        l += __shfl_xor(l, 16);
        l += __shfl_xor(l, 32);
        lp[rb] = l;
        if (lane < 16) lpx[wave][rb][l16] = l;
    }
    __syncthreads();  // all waves done with pbuf -> xbuf overlay safe; lpx visible
#pragma unroll
    for (int rb = 0; rb < 2; ++rb)
        inv[rb] = __builtin_amdgcn_rcpf(lp[rb] + lpx[wave ^ 2][rb][l16]);

    // 4-phase merge over g = (ks,dir) into xbuf; g==0 stores. 32 rows x 64 lanes.
    const int g = (ks << 1) | dir;
#pragma unroll 1
    for (int ph = 3; ph >= 1; --ph) {
        if (g == ph) {
#pragma unroll
            for (int rb = 0; rb < 2; ++rb)
#pragma unroll
                for (int ct = 0; ct < 4; ++ct)
#pragma unroll
                    for (int r = 0; r < 4; ++r) {
                        const int slot = (rb * 16 + ct * 4 + r) * 64 + lane;
                        float v = accO[rb][ct][r] * inv[rb];
                        if (ph == 3) xbuf[slot] = v;
                        else xbuf[slot] += v;
                    }
        }
        __syncthreads();
    }
    if (g == 0) {
        float* ob = out + (size_t)b * plane;
#pragma unroll
        for (int rb = 0; rb < 2; ++rb)
#pragma unroll
            for (int ct = 0; ct < 4; ++ct)
#pragma unroll
                for (int r = 0; r < 4; ++r) {
                    float v = accO[rb][ct][r] * inv[rb] +
                              xbuf[(rb * 16 + ct * 4 + r) * 64 + lane];
                    // out[c = ct*16+quad*4+r][t = q0+rb*16+l16]: coalesced over l16
                    ob[(size_t)(ct * 16 + quad * 4 + r) * TT + q0 + rb * 16 + l16] = v;
                }
    }
}

extern "C" void kernel_launch(void* const* d_in, const int* in_sizes, int n_in,
                              void* d_out, int out_size, void* d_ws, size_t ws_size,
                              hipStream_t stream) {
    const float* x1 = (const float*)d_in[0];
    const float* x2 = (const float*)d_in[1];
    ushort* kt = (ushort*)d_ws;                              // 8 MB frag-packed K/Q
    ushort* vt = (ushort*)d_ws + (size_t)2 * NB * TT * CC;   // 8 MB frag-packed V

    hipLaunchKernelGGL(prep_k, dim3(TT / 64, NB, 2), dim3(256), 0, stream, x1, x2, kt, vt);
    hipLaunchKernelGGL(attn_fused_k, dim3(64 * NB * 2), dim3(256), 0, stream,
                       kt, vt, (float*)d_out);
}

// Round 11
// 172.216 us; speedup vs baseline: 2.5091x; 1.0457x over previous
//
#include <hip/hip_runtime.h>
#include <hip/hip_bf16.h>
#include <stdint.h>

// MutualCrossAttention: B=8, C=64, H=W=64 -> T=4096 tokens. Inputs FP32, output FP32.
// dir A: Q=x1, K=V=x2 ; dir B: Q=x2, K=V=x1 ; out = outA + outB, layout [b][c][t].
// R23 = R22 RESUBMITTED UNCHANGED (R10's bench was an infrastructure failure:
// "MI355X container failed twice" — kernel never ran; no signal to update on).
// R22 = R18 (frag-packed K/V/Q, K ping-pong + V named-reg prefetch, (512,2),
// best measured 120us attn) WITH THE IN-LOOP BARRIERS REMOVED. hipcc emits
// s_waitcnt vmcnt(0) lgkmcnt(0) before every s_barrier, so R18's barriers were
// force-draining every prefetch 64x/block — the pipeline never actually ran as
// counted-vmcnt. With no barriers the issue order (kB -> V -> kA -> V ...)
// yields textbook counted waits: S(kB) waits vmcnt(16) (V+kA stay in flight),
// PV waits vmcnt(8) (kA stays in flight). pbuf is wave-private, so the loop
// needs NO synchronization; the epilogue's first __syncthreads (before the
// xbuf overlay / lpx reads) joins all waves after their last pbuf use.
// R13's free-run failure does not apply: that kernel had 16-cache-line scatter
// loads; R18's packed layout makes every load a contiguous 1KB block (L2 ~200cy,
// fully covered by the prefetch depth). Occupancy chasing is abandoned: R19/R20/
// R21 proved resident waves are pinned ~8/CU unless min-waves attrs wreck the
// register budget. ILP per wave is the lever.
//   kt chunk(tt,mt,ch):  lane(quad,l16) holds K[t=tt*64+mt*16+l16][c=ch*32+quad*8+e]
//   vt chunk(tt,ch2,ct): lane(quad,l16) holds V[c=ct*16+l16][t=tt*64+ch2*32+quad*8+e]
// Q frags are kt chunks at (qt, mt=pair*2+rb, ch) — all hot loads contiguous 1KB.
//   - S^T composition (A=K,B=Q then A=V,B=P^T): P^T C/D layout gives 4
//     consecutive tokens/lane -> b64 pbuf write, b128 read, stride-72.
//   - lp is one scalar per lane (q = l16 column), butterflied over quads.
//   - O^T epilogue: row=c, col=q -> scalar f32 stores coalesced over l16.
// ws: [0,8MB) kt bf16 frag-packed {x1,x2} PRE-SCALED by sqrt(log2(e)/8);
//     [8MB,16MB) vt bf16 frag-packed {x1,x2} unscaled.

#define TT 4096
#define CC 64
#define NB 8

typedef float f32x4 __attribute__((ext_vector_type(4)));
typedef float f32x4a __attribute__((ext_vector_type(4), may_alias));
typedef short s16x8 __attribute__((ext_vector_type(8)));
typedef unsigned int u32x2a __attribute__((ext_vector_type(2), may_alias));
typedef unsigned int u32x4a __attribute__((ext_vector_type(4), may_alias));
typedef float f32a __attribute__((may_alias));

static __device__ __forceinline__ unsigned fbits(float x) { return __float_as_uint(x); }
static __device__ __forceinline__ ushort bf16of(float v) {
    return (ushort)((fbits(v) + 0x8000u) >> 16);
}
static __device__ __forceinline__ unsigned pack2(float a, float b) {
    return __builtin_amdgcn_perm(fbits(b) + 0x8000u, fbits(a) + 0x8000u, 0x07060302u);
}
static __device__ __forceinline__ s16x8 load_frag(const void* p) {
    u32x4a t = *(const u32x4a*)p;
    return __builtin_bit_cast(s16x8, t);
}

#define SQC1 0.4246609177f  // sqrt(log2(e)/8), applied to kt on both Q and K sides

// grid (TT/64, NB, 2), 256 threads. Reads c-major f32, emits frag-packed bf16.
__global__ void prep_k(const float* __restrict__ x1, const float* __restrict__ x2,
                       ushort* __restrict__ kt, ushort* __restrict__ vt) {
    const int inp = blockIdx.z, b = blockIdx.y, tt = blockIdx.x;
    const float* src = (inp == 0 ? x1 : x2) + (size_t)b * CC * TT;
    const size_t plane = (size_t)TT * CC;
    ushort* kd = kt + (size_t)(inp * NB + b) * plane;
    ushort* vd = vt + (size_t)(inp * NB + b) * plane;
    __shared__ ushort lds[64][72];
    const int tid = threadIdx.x;
    const int c  = tid >> 2;        // 0..63: channel row
    const int tg = tid & 3;         // 16-token group within the 64-token tile
    const float* srow = src + (size_t)c * TT + tt * 64 + tg * 16;
    unsigned hw[8];
#pragma unroll
    for (int i = 0; i < 4; ++i) {
        f32x4a v = *(const f32x4a*)(srow + i * 4);
        hw[2 * i]     = pack2(v[0], v[1]);
        hw[2 * i + 1] = pack2(v[2], v[3]);
#pragma unroll
        for (int k = 0; k < 4; ++k) lds[tg * 16 + i * 4 + k][c] = bf16of(v[k] * SQC1);
    }
    // vt frag-packed (unscaled): thread(c,tg) owns V[c][t_local=tg*16..+16] =
    // chunk(tt, ch2=tg>>1, ct=c>>4), lanes (quad=(tg&1)*2 and +1, l16=c&15).
    {
        ushort* vchunk = vd + (((size_t)tt * 2 + (tg >> 1)) * 4 + (c >> 4)) * 512;
        const int l16v = c & 15;
        const int q0v  = (tg & 1) * 2;
        u32x4a w0 = {hw[0], hw[1], hw[2], hw[3]};
        u32x4a w1 = {hw[4], hw[5], hw[6], hw[7]};
        *(u32x4a*)(vchunk + (size_t)(q0v * 16 + l16v) * 8)       = w0;
        *(u32x4a*)(vchunk + (size_t)((q0v + 1) * 16 + l16v) * 8) = w1;
    }
    __syncthreads();
    // kt frag-packed (scaled, from transposed LDS): tid = mt*64 + quad*16 + l16.
    // chunk(tt, mt, ch): lane holds 8 consecutive c at row t = mt*16 + l16.
    const int mt   = tid >> 6;
    const int quad = (tid >> 4) & 3;
    const int l16  = tid & 15;
    const int t    = mt * 16 + l16;
#pragma unroll
    for (int ch = 0; ch < 2; ++ch) {
        u32x4a w = *(const u32x4a*)&lds[t][ch * 32 + quad * 8];
        *(u32x4a*)(kd + (((size_t)tt * 4 + mt) * 2 + ch) * 512 +
                   (size_t)(quad * 16 + l16) * 8) = w;
    }
}

// grid = 512 blocks (qt 0..63 x b 0..7), 512 threads = 8 waves.
// wave: dir = w&1, pair = (w>>1)&1, ks = w>>2 (2048-token half).
__global__ __launch_bounds__(512, 2)
void attn_fused_k(const ushort* __restrict__ kt, const ushort* __restrict__ vt,
                  float* __restrict__ out) {
    const int b    = blockIdx.x & 7;
    const int qt   = blockIdx.x >> 3;
    const int tid  = threadIdx.x;
    const int wave = tid >> 6;
    const int lane = tid & 63;
    const int quad = lane >> 4;
    const int l16  = lane & 15;
    const int dir  = wave & 1;
    const int pair = (wave >> 1) & 1;
    const int ks   = wave >> 2;
    const int q0   = qt * 64 + pair * 32;

    const size_t plane = (size_t)TT * CC;
    // All hot-loop loads: base + chunk*512 + lane*8 (ushorts) = contiguous 1KB/instr.
    const ushort* Qp = kt + (size_t)((dir == 0 ? 0 : NB) + b) * plane + (size_t)lane * 8;
    const ushort* Kp = kt + (size_t)((dir == 0 ? NB : 0) + b) * plane + (size_t)lane * 8;
    const ushort* Vp = vt + (size_t)((dir == 0 ? NB : 0) + b) * plane + (size_t)lane * 8;

    __shared__ __align__(16) ushort pbuf[8][2][16][72];    // 36.9 KB (q rows, tok cols)
    __shared__ float lpx[8][2][16];                        // 1 KB
    f32a* xbuf = (f32a*)&pbuf[0][0][0][0];                 // 16 KB overlay, post-loop

    // Q b-frags = kt chunks (qt, mt = pair*2 + rb, ch), pre-scaled.
    s16x8 qf[2][2];
#pragma unroll
    for (int rb = 0; rb < 2; ++rb)
#pragma unroll
        for (int ch = 0; ch < 2; ++ch)
            qf[rb][ch] = load_frag(Qp + (((size_t)qt * 4 + pair * 2 + rb) * 2 + ch) * 512);

    f32x4 accO[2][4];  // O^T partial: row=c=quad*4+r (+ct*16), col=q=l16 (+rb*16)
#pragma unroll
    for (int rb = 0; rb < 2; ++rb)
#pragma unroll
        for (int ct = 0; ct < 4; ++ct) accO[rb][ct] = (f32x4){0.f, 0.f, 0.f, 0.f};
    float lp[2] = {0.f, 0.f};

    // Named registers only (R14/R15 lesson: arrays spill under pressure).
    s16x8 kA0, kA1, kA2, kA3, kA4, kA5, kA6, kA7;   // K set A: chunks (mt,ch)
    s16x8 kB0, kB1, kB2, kB3, kB4, kB5, kB6, kB7;   // K set B
    s16x8 v0, v1, v2, v3, v4, v5, v6, v7;           // V: (ch2,ct)

    auto loadKA = [&](int j) {
        const ushort* p = Kp + (size_t)(ks * 32 + j) * 4096;
        kA0 = load_frag(p);          kA1 = load_frag(p + 512);
        kA2 = load_frag(p + 1024);   kA3 = load_frag(p + 1536);
        kA4 = load_frag(p + 2048);   kA5 = load_frag(p + 2560);
        kA6 = load_frag(p + 3072);   kA7 = load_frag(p + 3584);
    };
    auto loadKB = [&](int j) {
        const ushort* p = Kp + (size_t)(ks * 32 + j) * 4096;
        kB0 = load_frag(p);          kB1 = load_frag(p + 512);
        kB2 = load_frag(p + 1024);   kB3 = load_frag(p + 1536);
        kB4 = load_frag(p + 2048);   kB5 = load_frag(p + 2560);
        kB6 = load_frag(p + 3072);   kB7 = load_frag(p + 3584);
    };
    auto loadV = [&](int j) {
        const ushort* p = Vp + (size_t)(ks * 32 + j) * 4096;
        v0 = load_frag(p);           v1 = load_frag(p + 512);
        v2 = load_frag(p + 1024);    v3 = load_frag(p + 1536);
        v4 = load_frag(p + 2048);    v5 = load_frag(p + 2560);
        v6 = load_frag(p + 3072);    v7 = load_frag(p + 3584);
    };

    // One mt-slice of S^T: D[row=tok=quad*4+r (+mt*16)][col=q=l16] -> b64 P write.
    auto SmT = [&](s16x8 kc0, s16x8 kc1, int mt) {
#pragma unroll
        for (int rb = 0; rb < 2; ++rb) {
            f32x4 s = (f32x4){0.f, 0.f, 0.f, 0.f};
            s = __builtin_amdgcn_mfma_f32_16x16x32_bf16(kc0, qf[rb][0], s, 0, 0, 0);
            s = __builtin_amdgcn_mfma_f32_16x16x32_bf16(kc1, qf[rb][1], s, 0, 0, 0);
            float p0 = __builtin_amdgcn_exp2f(s[0]);
            float p1 = __builtin_amdgcn_exp2f(s[1]);
            float p2 = __builtin_amdgcn_exp2f(s[2]);
            float p3 = __builtin_amdgcn_exp2f(s[3]);
            lp[rb] += (p0 + p1) + (p2 + p3);
            u32x2a w;
            w[0] = pack2(p0, p1);
            w[1] = pack2(p2, p3);
            *(u32x2a*)&pbuf[wave][rb][l16][mt * 16 + quad * 4] = w;
        }
    };
    // PV(j): A = V (prefetched named regs) [m=c=l16(+ct*16)][k=tok],
    //        B = P^T [n=q=l16][k=tok] (b128 LDS read). Pure reg-MFMA otherwise.
    auto PVphase = [&]() {
        s16x8 pf0a = load_frag(&pbuf[wave][0][l16][quad * 8]);
        s16x8 pf1a = load_frag(&pbuf[wave][1][l16][quad * 8]);
        accO[0][0] = __builtin_amdgcn_mfma_f32_16x16x32_bf16(v0, pf0a, accO[0][0], 0, 0, 0);
        accO[1][0] = __builtin_amdgcn_mfma_f32_16x16x32_bf16(v0, pf1a, accO[1][0], 0, 0, 0);
        accO[0][1] = __builtin_amdgcn_mfma_f32_16x16x32_bf16(v1, pf0a, accO[0][1], 0, 0, 0);
        accO[1][1] = __builtin_amdgcn_mfma_f32_16x16x32_bf16(v1, pf1a, accO[1][1], 0, 0, 0);
        accO[0][2] = __builtin_amdgcn_mfma_f32_16x16x32_bf16(v2, pf0a, accO[0][2], 0, 0, 0);
        accO[1][2] = __builtin_amdgcn_mfma_f32_16x16x32_bf16(v2, pf1a, accO[1][2], 0, 0, 0);
        accO[0][3] = __builtin_amdgcn_mfma_f32_16x16x32_bf16(v3, pf0a, accO[0][3], 0, 0, 0);
        accO[1][3] = __builtin_amdgcn_mfma_f32_16x16x32_bf16(v3, pf1a, accO[1][3], 0, 0, 0);
        s16x8 pf0b = load_frag(&pbuf[wave][0][l16][32 + quad * 8]);
        s16x8 pf1b = load_frag(&pbuf[wave][1][l16][32 + quad * 8]);
        accO[0][0] = __builtin_amdgcn_mfma_f32_16x16x32_bf16(v4, pf0b, accO[0][0], 0, 0, 0);
        accO[1][0] = __builtin_amdgcn_mfma_f32_16x16x32_bf16(v4, pf1b, accO[1][0], 0, 0, 0);
        accO[0][1] = __builtin_amdgcn_mfma_f32_16x16x32_bf16(v5, pf0b, accO[0][1], 0, 0, 0);
        accO[1][1] = __builtin_amdgcn_mfma_f32_16x16x32_bf16(v5, pf1b, accO[1][1], 0, 0, 0);
        accO[0][2] = __builtin_amdgcn_mfma_f32_16x16x32_bf16(v6, pf0b, accO[0][2], 0, 0, 0);
        accO[1][2] = __builtin_amdgcn_mfma_f32_16x16x32_bf16(v6, pf1b, accO[1][2], 0, 0, 0);
        accO[0][3] = __builtin_amdgcn_mfma_f32_16x16x32_bf16(v7, pf0b, accO[0][3], 0, 0, 0);
        accO[1][3] = __builtin_amdgcn_mfma_f32_16x16x32_bf16(v7, pf1b, accO[1][3], 0, 0, 0);
    };

    // BARRIER-FREE ping-pong pipeline, unroll 2. Issue order per iter:
    //   loadKB(j+1) -> S(kA) -> PV(j) [waits vmcnt: V done, kB in flight]
    //   -> loadV(j+1) -> loadKA(j+2) -> S(kB) [waits vmcnt(16): kB done,
    //      V+kA in flight] -> PV(j+1) [waits vmcnt(8): V done, kA in flight]
    //   -> loadV(j+2).
    // No s_barrier => no compiler-forced vmcnt(0) drain; every prefetch keeps
    // a full S+PV phase of cover. pbuf is wave-private (in-order DS per wave).
    loadKA(0);
    loadV(0);
#pragma unroll 1
    for (int j = 0; j < 32; j += 2) {
        loadKB(j + 1);
        SmT(kA0, kA1, 0); SmT(kA2, kA3, 1); SmT(kA4, kA5, 2); SmT(kA6, kA7, 3);
        PVphase();                       // PV(j)
        loadV(j + 1);
        if (j + 2 < 32) loadKA(j + 2);
        SmT(kB0, kB1, 0); SmT(kB2, kB3, 1); SmT(kB4, kB5, 2); SmT(kB6, kB7, 3);
        PVphase();                       // PV(j+1)
        if (j + 2 < 32) loadV(j + 2);
    }

    // Denominator: quads hold disjoint token subsets for col q=l16.
    float inv[2];
#pragma unroll
    for (int rb = 0; rb < 2; ++rb) {
        float l = lp[rb];
        l += __shfl_xor(l, 16);
        l += __shfl_xor(l, 32);
        lp[rb] = l;
        if (lane < 16) lpx[wave][rb][l16] = l;
    }
    __syncthreads();  // joins ALL waves after their last pbuf use ->
                      // xbuf overlay safe; lpx visible
#pragma unroll
    for (int rb = 0; rb < 2; ++rb)
        inv[rb] = __builtin_amdgcn_rcpf(lp[rb] + lpx[wave ^ 4][rb][l16]);

    // 4-phase merge over g = (ks,dir) into xbuf[pair]; g==0 stores.
    const int g = (ks << 1) | dir;
#pragma unroll 1
    for (int ph = 3; ph >= 1; --ph) {
        if (g == ph) {
#pragma unroll
            for (int rb = 0; rb < 2; ++rb)
#pragma unroll
                for (int ct = 0; ct < 4; ++ct)
#pragma unroll
                    for (int r = 0; r < 4; ++r) {
                        const int slot = (pair * 32 + rb * 16 + ct * 4 + r) * 64 + lane;
                        float v = accO[rb][ct][r] * inv[rb];
                        if (ph == 3) xbuf[slot] = v;
                        else xbuf[slot] += v;
                    }
        }
        __syncthreads();
    }
    if (g == 0) {
        float* ob = out + (size_t)b * plane;
#pragma unroll
        for (int rb = 0; rb < 2; ++rb)
#pragma unroll
            for (int ct = 0; ct < 4; ++ct)
#pragma unroll
                for (int r = 0; r < 4; ++r) {
                    float v = accO[rb][ct][r] * inv[rb] +
                              xbuf[(pair * 32 + rb * 16 + ct * 4 + r) * 64 + lane];
                    // out[c = ct*16+quad*4+r][t = q0+rb*16+l16]: coalesced over l16
                    ob[(size_t)(ct * 16 + quad * 4 + r) * TT + q0 + rb * 16 + l16] = v;
                }
    }
}

extern "C" void kernel_launch(void* const* d_in, const int* in_sizes, int n_in,
                              void* d_out, int out_size, void* d_ws, size_t ws_size,
                              hipStream_t stream) {
    const float* x1 = (const float*)d_in[0];
    const float* x2 = (const float*)d_in[1];
    ushort* kt = (ushort*)d_ws;                              // 8 MB frag-packed K/Q
    ushort* vt = (ushort*)d_ws + (size_t)2 * NB * TT * CC;   // 8 MB frag-packed V

    hipLaunchKernelGGL(prep_k, dim3(TT / 64, NB, 2), dim3(256), 0, stream, x1, x2, kt, vt);
    hipLaunchKernelGGL(attn_fused_k, dim3(64 * NB), dim3(512), 0, stream,
                       kt, vt, (float*)d_out);
}

// Round 12
// 171.099 us; speedup vs baseline: 2.5254x; 1.0065x over previous
//
#include <hip/hip_runtime.h>
#include <hip/hip_bf16.h>
#include <stdint.h>

// MutualCrossAttention: B=8, C=64, H=W=64 -> T=4096 tokens. Inputs FP32, output FP32.
// dir A: Q=x1, K=V=x2 ; dir B: Q=x2, K=V=x1 ; out = outA + outB, layout [b][c][t].
// R24 = R22/R23 (frag-packed K/V/Q, barrier-free counted-vmcnt ping-pong, best
// measured 116us attn) with the LAUNCH-BOUNDS DECLARATION REMOVED (only
// amdgpu_flat_work_group_size(512,512) kept). Occupancy model closing all 11
// rounds: compiler VGPR budget = 256/min_waves_declared; CP residency FOLLOWS
// the declaration (not physical fit): (512,2) -> 2 waves/SIMD always (21-22%
// at VGPR 64..108), (512,4)/(4,4) -> 4 waves/SIMD but budget 64 -> spill.
// The knobs are coupled: declared waves x budget = 256. But the PHYSICAL pool
// is ~512 VGPR/SIMD (m69: waves halve at 64/128/256; m97: 164 VGPR -> 3
// waves/SIMD with NO launch bounds). Escape hatch = declare nothing: compiler
// allocates what the kernel needs (~108), CP hosts floor-by-physical-fit
// (4 waves/SIMD = 2 blocks/CU = 44%) with zero spill. This is the only
// configuration giving BOTH the 108-reg pipeline AND 16 waves/CU.
//   kt chunk(tt,mt,ch):  lane(quad,l16) holds K[t=tt*64+mt*16+l16][c=ch*32+quad*8+e]
//   vt chunk(tt,ch2,ct): lane(quad,l16) holds V[c=ct*16+l16][t=tt*64+ch2*32+quad*8+e]
// Q frags are kt chunks at (qt, mt=pair*2+rb, ch) — all hot loads contiguous 1KB.
//   - Barrier-free loop: pbuf is wave-private; hipcc's forced vmcnt(0) drain
//     before s_barrier was nullifying the prefetch pipeline (R23 proved +4us).
//   - S^T composition (A=K,B=Q then A=V,B=P^T): P^T C/D layout gives 4
//     consecutive tokens/lane -> b64 pbuf write, b128 read, stride-72.
//   - lp is one scalar per lane (q = l16 column), butterflied over quads.
//   - O^T epilogue: row=c, col=q -> scalar f32 stores coalesced over l16.
// ws: [0,8MB) kt bf16 frag-packed {x1,x2} PRE-SCALED by sqrt(log2(e)/8);
//     [8MB,16MB) vt bf16 frag-packed {x1,x2} unscaled.

#define TT 4096
#define CC 64
#define NB 8

typedef float f32x4 __attribute__((ext_vector_type(4)));
typedef float f32x4a __attribute__((ext_vector_type(4), may_alias));
typedef short s16x8 __attribute__((ext_vector_type(8)));
typedef unsigned int u32x2a __attribute__((ext_vector_type(2), may_alias));
typedef unsigned int u32x4a __attribute__((ext_vector_type(4), may_alias));
typedef float f32a __attribute__((may_alias));

static __device__ __forceinline__ unsigned fbits(float x) { return __float_as_uint(x); }
static __device__ __forceinline__ ushort bf16of(float v) {
    return (ushort)((fbits(v) + 0x8000u) >> 16);
}
static __device__ __forceinline__ unsigned pack2(float a, float b) {
    return __builtin_amdgcn_perm(fbits(b) + 0x8000u, fbits(a) + 0x8000u, 0x07060302u);
}
static __device__ __forceinline__ s16x8 load_frag(const void* p) {
    u32x4a t = *(const u32x4a*)p;
    return __builtin_bit_cast(s16x8, t);
}

#define SQC1 0.4246609177f  // sqrt(log2(e)/8), applied to kt on both Q and K sides

// grid (TT/64, NB, 2), 256 threads. Reads c-major f32, emits frag-packed bf16.
__global__ void prep_k(const float* __restrict__ x1, const float* __restrict__ x2,
                       ushort* __restrict__ kt, ushort* __restrict__ vt) {
    const int inp = blockIdx.z, b = blockIdx.y, tt = blockIdx.x;
    const float* src = (inp == 0 ? x1 : x2) + (size_t)b * CC * TT;
    const size_t plane = (size_t)TT * CC;
    ushort* kd = kt + (size_t)(inp * NB + b) * plane;
    ushort* vd = vt + (size_t)(inp * NB + b) * plane;
    __shared__ ushort lds[64][72];
    const int tid = threadIdx.x;
    const int c  = tid >> 2;        // 0..63: channel row
    const int tg = tid & 3;         // 16-token group within the 64-token tile
    const float* srow = src + (size_t)c * TT + tt * 64 + tg * 16;
    unsigned hw[8];
#pragma unroll
    for (int i = 0; i < 4; ++i) {
        f32x4a v = *(const f32x4a*)(srow + i * 4);
        hw[2 * i]     = pack2(v[0], v[1]);
        hw[2 * i + 1] = pack2(v[2], v[3]);
#pragma unroll
        for (int k = 0; k < 4; ++k) lds[tg * 16 + i * 4 + k][c] = bf16of(v[k] * SQC1);
    }
    // vt frag-packed (unscaled): thread(c,tg) owns V[c][t_local=tg*16..+16] =
    // chunk(tt, ch2=tg>>1, ct=c>>4), lanes (quad=(tg&1)*2 and +1, l16=c&15).
    {
        ushort* vchunk = vd + (((size_t)tt * 2 + (tg >> 1)) * 4 + (c >> 4)) * 512;
        const int l16v = c & 15;
        const int q0v  = (tg & 1) * 2;
        u32x4a w0 = {hw[0], hw[1], hw[2], hw[3]};
        u32x4a w1 = {hw[4], hw[5], hw[6], hw[7]};
        *(u32x4a*)(vchunk + (size_t)(q0v * 16 + l16v) * 8)       = w0;
        *(u32x4a*)(vchunk + (size_t)((q0v + 1) * 16 + l16v) * 8) = w1;
    }
    __syncthreads();
    // kt frag-packed (scaled, from transposed LDS): tid = mt*64 + quad*16 + l16.
    // chunk(tt, mt, ch): lane holds 8 consecutive c at row t = mt*16 + l16.
    const int mt   = tid >> 6;
    const int quad = (tid >> 4) & 3;
    const int l16  = tid & 15;
    const int t    = mt * 16 + l16;
#pragma unroll
    for (int ch = 0; ch < 2; ++ch) {
        u32x4a w = *(const u32x4a*)&lds[t][ch * 32 + quad * 8];
        *(u32x4a*)(kd + (((size_t)tt * 4 + mt) * 2 + ch) * 512 +
                   (size_t)(quad * 16 + l16) * 8) = w;
    }
}

// grid = 512 blocks (qt 0..63 x b 0..7), 512 threads = 8 waves.
// wave: dir = w&1, pair = (w>>1)&1, ks = w>>2 (2048-token half).
// NO waves-per-EU declaration: compiler allocates demand (~108 VGPR), CP
// schedules by physical fit (512-VGPR/SIMD pool -> 4 waves/SIMD -> 2 blk/CU).
__global__ __attribute__((amdgpu_flat_work_group_size(512, 512)))
void attn_fused_k(const ushort* __restrict__ kt, const ushort* __restrict__ vt,
                  float* __restrict__ out) {
    const int b    = blockIdx.x & 7;
    const int qt   = blockIdx.x >> 3;
    const int tid  = threadIdx.x;
    const int wave = tid >> 6;
    const int lane = tid & 63;
    const int quad = lane >> 4;
    const int l16  = lane & 15;
    const int dir  = wave & 1;
    const int pair = (wave >> 1) & 1;
    const int ks   = wave >> 2;
    const int q0   = qt * 64 + pair * 32;

    const size_t plane = (size_t)TT * CC;
    // All hot-loop loads: base + chunk*512 + lane*8 (ushorts) = contiguous 1KB/instr.
    const ushort* Qp = kt + (size_t)((dir == 0 ? 0 : NB) + b) * plane + (size_t)lane * 8;
    const ushort* Kp = kt + (size_t)((dir == 0 ? NB : 0) + b) * plane + (size_t)lane * 8;
    const ushort* Vp = vt + (size_t)((dir == 0 ? NB : 0) + b) * plane + (size_t)lane * 8;

    __shared__ __align__(16) ushort pbuf[8][2][16][72];    // 36.9 KB (q rows, tok cols)
    __shared__ float lpx[8][2][16];                        // 1 KB
    f32a* xbuf = (f32a*)&pbuf[0][0][0][0];                 // 16 KB overlay, post-loop

    // Q b-frags = kt chunks (qt, mt = pair*2 + rb, ch), pre-scaled.
    s16x8 qf[2][2];
#pragma unroll
    for (int rb = 0; rb < 2; ++rb)
#pragma unroll
        for (int ch = 0; ch < 2; ++ch)
            qf[rb][ch] = load_frag(Qp + (((size_t)qt * 4 + pair * 2 + rb) * 2 + ch) * 512);

    f32x4 accO[2][4];  // O^T partial: row=c=quad*4+r (+ct*16), col=q=l16 (+rb*16)
#pragma unroll
    for (int rb = 0; rb < 2; ++rb)
#pragma unroll
        for (int ct = 0; ct < 4; ++ct) accO[rb][ct] = (f32x4){0.f, 0.f, 0.f, 0.f};
    float lp[2] = {0.f, 0.f};

    // Named registers only (R14/R15 lesson: arrays spill under pressure).
    s16x8 kA0, kA1, kA2, kA3, kA4, kA5, kA6, kA7;   // K set A: chunks (mt,ch)
    s16x8 kB0, kB1, kB2, kB3, kB4, kB5, kB6, kB7;   // K set B
    s16x8 v0, v1, v2, v3, v4, v5, v6, v7;           // V: (ch2,ct)

    auto loadKA = [&](int j) {
        const ushort* p = Kp + (size_t)(ks * 32 + j) * 4096;
        kA0 = load_frag(p);          kA1 = load_frag(p + 512);
        kA2 = load_frag(p + 1024);   kA3 = load_frag(p + 1536);
        kA4 = load_frag(p + 2048);   kA5 = load_frag(p + 2560);
        kA6 = load_frag(p + 3072);   kA7 = load_frag(p + 3584);
    };
    auto loadKB = [&](int j) {
        const ushort* p = Kp + (size_t)(ks * 32 + j) * 4096;
        kB0 = load_frag(p);          kB1 = load_frag(p + 512);
        kB2 = load_frag(p + 1024);   kB3 = load_frag(p + 1536);
        kB4 = load_frag(p + 2048);   kB5 = load_frag(p + 2560);
        kB6 = load_frag(p + 3072);   kB7 = load_frag(p + 3584);
    };
    auto loadV = [&](int j) {
        const ushort* p = Vp + (size_t)(ks * 32 + j) * 4096;
        v0 = load_frag(p);           v1 = load_frag(p + 512);
        v2 = load_frag(p + 1024);    v3 = load_frag(p + 1536);
        v4 = load_frag(p + 2048);    v5 = load_frag(p + 2560);
        v6 = load_frag(p + 3072);    v7 = load_frag(p + 3584);
    };

    // One mt-slice of S^T: D[row=tok=quad*4+r (+mt*16)][col=q=l16] -> b64 P write.
    auto SmT = [&](s16x8 kc0, s16x8 kc1, int mt) {
#pragma unroll
        for (int rb = 0; rb < 2; ++rb) {
            f32x4 s = (f32x4){0.f, 0.f, 0.f, 0.f};
            s = __builtin_amdgcn_mfma_f32_16x16x32_bf16(kc0, qf[rb][0], s, 0, 0, 0);
            s = __builtin_amdgcn_mfma_f32_16x16x32_bf16(kc1, qf[rb][1], s, 0, 0, 0);
            float p0 = __builtin_amdgcn_exp2f(s[0]);
            float p1 = __builtin_amdgcn_exp2f(s[1]);
            float p2 = __builtin_amdgcn_exp2f(s[2]);
            float p3 = __builtin_amdgcn_exp2f(s[3]);
            lp[rb] += (p0 + p1) + (p2 + p3);
            u32x2a w;
            w[0] = pack2(p0, p1);
            w[1] = pack2(p2, p3);
            *(u32x2a*)&pbuf[wave][rb][l16][mt * 16 + quad * 4] = w;
        }
    };
    // PV(j): A = V (prefetched named regs) [m=c=l16(+ct*16)][k=tok],
    //        B = P^T [n=q=l16][k=tok] (b128 LDS read). Pure reg-MFMA otherwise.
    auto PVphase = [&]() {
        s16x8 pf0a = load_frag(&pbuf[wave][0][l16][quad * 8]);
        s16x8 pf1a = load_frag(&pbuf[wave][1][l16][quad * 8]);
        accO[0][0] = __builtin_amdgcn_mfma_f32_16x16x32_bf16(v0, pf0a, accO[0][0], 0, 0, 0);
        accO[1][0] = __builtin_amdgcn_mfma_f32_16x16x32_bf16(v0, pf1a, accO[1][0], 0, 0, 0);
        accO[0][1] = __builtin_amdgcn_mfma_f32_16x16x32_bf16(v1, pf0a, accO[0][1], 0, 0, 0);
        accO[1][1] = __builtin_amdgcn_mfma_f32_16x16x32_bf16(v1, pf1a, accO[1][1], 0, 0, 0);
        accO[0][2] = __builtin_amdgcn_mfma_f32_16x16x32_bf16(v2, pf0a, accO[0][2], 0, 0, 0);
        accO[1][2] = __builtin_amdgcn_mfma_f32_16x16x32_bf16(v2, pf1a, accO[1][2], 0, 0, 0);
        accO[0][3] = __builtin_amdgcn_mfma_f32_16x16x32_bf16(v3, pf0a, accO[0][3], 0, 0, 0);
        accO[1][3] = __builtin_amdgcn_mfma_f32_16x16x32_bf16(v3, pf1a, accO[1][3], 0, 0, 0);
        s16x8 pf0b = load_frag(&pbuf[wave][0][l16][32 + quad * 8]);
        s16x8 pf1b = load_frag(&pbuf[wave][1][l16][32 + quad * 8]);
        accO[0][0] = __builtin_amdgcn_mfma_f32_16x16x32_bf16(v4, pf0b, accO[0][0], 0, 0, 0);
        accO[1][0] = __builtin_amdgcn_mfma_f32_16x16x32_bf16(v4, pf1b, accO[1][0], 0, 0, 0);
        accO[0][1] = __builtin_amdgcn_mfma_f32_16x16x32_bf16(v5, pf0b, accO[0][1], 0, 0, 0);
        accO[1][1] = __builtin_amdgcn_mfma_f32_16x16x32_bf16(v5, pf1b, accO[1][1], 0, 0, 0);
        accO[0][2] = __builtin_amdgcn_mfma_f32_16x16x32_bf16(v6, pf0b, accO[0][2], 0, 0, 0);
        accO[1][2] = __builtin_amdgcn_mfma_f32_16x16x32_bf16(v6, pf1b, accO[1][2], 0, 0, 0);
        accO[0][3] = __builtin_amdgcn_mfma_f32_16x16x32_bf16(v7, pf0b, accO[0][3], 0, 0, 0);
        accO[1][3] = __builtin_amdgcn_mfma_f32_16x16x32_bf16(v7, pf1b, accO[1][3], 0, 0, 0);
    };

    // BARRIER-FREE ping-pong pipeline, unroll 2. Issue order per iter:
    //   loadKB(j+1) -> S(kA) -> PV(j) [waits vmcnt: V done, kB in flight]
    //   -> loadV(j+1) -> loadKA(j+2) -> S(kB) [waits vmcnt(16): kB done,
    //      V+kA in flight] -> PV(j+1) [waits vmcnt(8): V done, kA in flight]
    //   -> loadV(j+2).
    // No s_barrier => no compiler-forced vmcnt(0) drain; every prefetch keeps
    // a full S+PV phase of cover. pbuf is wave-private (in-order DS per wave).
    loadKA(0);
    loadV(0);
#pragma unroll 1
    for (int j = 0; j < 32; j += 2) {
        loadKB(j + 1);
        SmT(kA0, kA1, 0); SmT(kA2, kA3, 1); SmT(kA4, kA5, 2); SmT(kA6, kA7, 3);
        PVphase();                       // PV(j)
        loadV(j + 1);
        if (j + 2 < 32) loadKA(j + 2);
        SmT(kB0, kB1, 0); SmT(kB2, kB3, 1); SmT(kB4, kB5, 2); SmT(kB6, kB7, 3);
        PVphase();                       // PV(j+1)
        if (j + 2 < 32) loadV(j + 2);
    }

    // Denominator: quads hold disjoint token subsets for col q=l16.
    float inv[2];
#pragma unroll
    for (int rb = 0; rb < 2; ++rb) {
        float l = lp[rb];
        l += __shfl_xor(l, 16);
        l += __shfl_xor(l, 32);
        lp[rb] = l;
        if (lane < 16) lpx[wave][rb][l16] = l;
    }
    __syncthreads();  // joins ALL waves after their last pbuf use ->
                      // xbuf overlay safe; lpx visible
#pragma unroll
    for (int rb = 0; rb < 2; ++rb)
        inv[rb] = __builtin_amdgcn_rcpf(lp[rb] + lpx[wave ^ 4][rb][l16]);

    // 4-phase merge over g = (ks,dir) into xbuf[pair]; g==0 stores.
    const int g = (ks << 1) | dir;
#pragma unroll 1
    for (int ph = 3; ph >= 1; --ph) {
        if (g == ph) {
#pragma unroll
            for (int rb = 0; rb < 2; ++rb)
#pragma unroll
                for (int ct = 0; ct < 4; ++ct)
#pragma unroll
                    for (int r = 0; r < 4; ++r) {
                        const int slot = (pair * 32 + rb * 16 + ct * 4 + r) * 64 + lane;
                        float v = accO[rb][ct][r] * inv[rb];
                        if (ph == 3) xbuf[slot] = v;
                        else xbuf[slot] += v;
                    }
        }
        __syncthreads();
    }
    if (g == 0) {
        float* ob = out + (size_t)b * plane;
#pragma unroll
        for (int rb = 0; rb < 2; ++rb)
#pragma unroll
            for (int ct = 0; ct < 4; ++ct)
#pragma unroll
                for (int r = 0; r < 4; ++r) {
                    float v = accO[rb][ct][r] * inv[rb] +
                              xbuf[(pair * 32 + rb * 16 + ct * 4 + r) * 64 + lane];
                    // out[c = ct*16+quad*4+r][t = q0+rb*16+l16]: coalesced over l16
                    ob[(size_t)(ct * 16 + quad * 4 + r) * TT + q0 + rb * 16 + l16] = v;
                }
    }
}

extern "C" void kernel_launch(void* const* d_in, const int* in_sizes, int n_in,
                              void* d_out, int out_size, void* d_ws, size_t ws_size,
                              hipStream_t stream) {
    const float* x1 = (const float*)d_in[0];
    const float* x2 = (const float*)d_in[1];
    ushort* kt = (ushort*)d_ws;                              // 8 MB frag-packed K/Q
    ushort* vt = (ushort*)d_ws + (size_t)2 * NB * TT * CC;   // 8 MB frag-packed V

    hipLaunchKernelGGL(prep_k, dim3(TT / 64, NB, 2), dim3(256), 0, stream, x1, x2, kt, vt);
    hipLaunchKernelGGL(attn_fused_k, dim3(64 * NB), dim3(512), 0, stream,
                       kt, vt, (float*)d_out);
}

// Round 13
// 163.621 us; speedup vs baseline: 2.6409x; 1.0457x over previous
//
#include <hip/hip_runtime.h>
#include <hip/hip_bf16.h>
#include <stdint.h>

// MutualCrossAttention: B=8, C=64, H=W=64 -> T=4096 tokens. Inputs FP32, output FP32.
// dir A: Q=x1, K=V=x2 ; dir B: Q=x2, K=V=x1 ; out = outA + outB, layout [b][c][t].
// R25 = R22/R24 (frag-packed K/V/Q, barrier-free counted-vmcnt loop, 116-118us
// attn) + PBUF PARITY DOUBLE-BUFFER to break the per-wave serial chain.
// Occupancy is pinned at 8 waves/CU (R19/R20/R21/R24: CP won't co-schedule a
// 2nd 512-thr block regardless of declaration/VGPR/LDS fit) -> per-CU j-phase
// budget is 4.4k cyc vs ~700 cyc of pipe-busy work: the kernel is bound by the
// per-wave chain S-MFMA -> exp2 -> pack -> pbuf write -> lgkm -> PV read -> PV-
// MFMA. Single pbuf region forced the in-order DS queue to serialize S(j+1)
// against PV(j). With pbuf[par = j&1], the 4 sub-phases per unrolled iter
//   S(j)->par0, S(j+1)->par1, PV(j)<-par0, PV(j+1)<-par1
// each depend only on work >= 1 phase older -> the scheduler can overlap
// S(j+1) compute with PV(j), and every pbuf write->read gets a full phase of
// slack instead of sitting on the critical path. V prefetch becomes 2 named
// sets (vA even / vB odd) so both stay WAR-safe across the reordered phases.
// All pieces proven: SmT/PVphase numerics, packed layout, barrier-free loop,
// epilogue merge. LDS 72KB pbuf + 1KB lpx (<=160). ~200 VGPR named regs, no
// launch bounds (R24: allocator sizes to demand; arrays would spill, R14/R15).
//   kt chunk(tt,mt,ch):  lane(quad,l16) holds K[t=tt*64+mt*16+l16][c=ch*32+quad*8+e]
//   vt chunk(tt,ch2,ct): lane(quad,l16) holds V[c=ct*16+l16][t=tt*64+ch2*32+quad*8+e]
// Q frags are kt chunks at (qt, mt=pair*2+rb, ch) — all hot loads contiguous 1KB.
//   - S^T composition (A=K,B=Q then A=V,B=P^T): P^T C/D layout gives 4
//     consecutive tokens/lane -> b64 pbuf write, b128 read, stride-72.
//   - lp is one scalar per lane (q = l16 column), butterflied over quads.
//   - O^T epilogue: row=c, col=q -> scalar f32 stores coalesced over l16.
// ws: [0,8MB) kt bf16 frag-packed {x1,x2} PRE-SCALED by sqrt(log2(e)/8);
//     [8MB,16MB) vt bf16 frag-packed {x1,x2} unscaled.

#define TT 4096
#define CC 64
#define NB 8

typedef float f32x4 __attribute__((ext_vector_type(4)));
typedef float f32x4a __attribute__((ext_vector_type(4), may_alias));
typedef short s16x8 __attribute__((ext_vector_type(8)));
typedef unsigned int u32x2a __attribute__((ext_vector_type(2), may_alias));
typedef unsigned int u32x4a __attribute__((ext_vector_type(4), may_alias));
typedef float f32a __attribute__((may_alias));

static __device__ __forceinline__ unsigned fbits(float x) { return __float_as_uint(x); }
static __device__ __forceinline__ ushort bf16of(float v) {
    return (ushort)((fbits(v) + 0x8000u) >> 16);
}
static __device__ __forceinline__ unsigned pack2(float a, float b) {
    return __builtin_amdgcn_perm(fbits(b) + 0x8000u, fbits(a) + 0x8000u, 0x07060302u);
}
static __device__ __forceinline__ s16x8 load_frag(const void* p) {
    u32x4a t = *(const u32x4a*)p;
    return __builtin_bit_cast(s16x8, t);
}

#define SQC1 0.4246609177f  // sqrt(log2(e)/8), applied to kt on both Q and K sides

// grid (TT/64, NB, 2), 256 threads. Reads c-major f32, emits frag-packed bf16.
__global__ void prep_k(const float* __restrict__ x1, const float* __restrict__ x2,
                       ushort* __restrict__ kt, ushort* __restrict__ vt) {
    const int inp = blockIdx.z, b = blockIdx.y, tt = blockIdx.x;
    const float* src = (inp == 0 ? x1 : x2) + (size_t)b * CC * TT;
    const size_t plane = (size_t)TT * CC;
    ushort* kd = kt + (size_t)(inp * NB + b) * plane;
    ushort* vd = vt + (size_t)(inp * NB + b) * plane;
    __shared__ ushort lds[64][72];
    const int tid = threadIdx.x;
    const int c  = tid >> 2;        // 0..63: channel row
    const int tg = tid & 3;         // 16-token group within the 64-token tile
    const float* srow = src + (size_t)c * TT + tt * 64 + tg * 16;
    unsigned hw[8];
#pragma unroll
    for (int i = 0; i < 4; ++i) {
        f32x4a v = *(const f32x4a*)(srow + i * 4);
        hw[2 * i]     = pack2(v[0], v[1]);
        hw[2 * i + 1] = pack2(v[2], v[3]);
#pragma unroll
        for (int k = 0; k < 4; ++k) lds[tg * 16 + i * 4 + k][c] = bf16of(v[k] * SQC1);
    }
    // vt frag-packed (unscaled): thread(c,tg) owns V[c][t_local=tg*16..+16] =
    // chunk(tt, ch2=tg>>1, ct=c>>4), lanes (quad=(tg&1)*2 and +1, l16=c&15).
    {
        ushort* vchunk = vd + (((size_t)tt * 2 + (tg >> 1)) * 4 + (c >> 4)) * 512;
        const int l16v = c & 15;
        const int q0v  = (tg & 1) * 2;
        u32x4a w0 = {hw[0], hw[1], hw[2], hw[3]};
        u32x4a w1 = {hw[4], hw[5], hw[6], hw[7]};
        *(u32x4a*)(vchunk + (size_t)(q0v * 16 + l16v) * 8)       = w0;
        *(u32x4a*)(vchunk + (size_t)((q0v + 1) * 16 + l16v) * 8) = w1;
    }
    __syncthreads();
    // kt frag-packed (scaled, from transposed LDS): tid = mt*64 + quad*16 + l16.
    // chunk(tt, mt, ch): lane holds 8 consecutive c at row t = mt*16 + l16.
    const int mt   = tid >> 6;
    const int quad = (tid >> 4) & 3;
    const int l16  = tid & 15;
    const int t    = mt * 16 + l16;
#pragma unroll
    for (int ch = 0; ch < 2; ++ch) {
        u32x4a w = *(const u32x4a*)&lds[t][ch * 32 + quad * 8];
        *(u32x4a*)(kd + (((size_t)tt * 4 + mt) * 2 + ch) * 512 +
                   (size_t)(quad * 16 + l16) * 8) = w;
    }
}

// grid = 512 blocks (qt 0..63 x b 0..7), 512 threads = 8 waves.
// wave: dir = w&1, pair = (w>>1)&1, ks = w>>2 (2048-token half).
__global__ __attribute__((amdgpu_flat_work_group_size(512, 512)))
void attn_fused_k(const ushort* __restrict__ kt, const ushort* __restrict__ vt,
                  float* __restrict__ out) {
    const int b    = blockIdx.x & 7;
    const int qt   = blockIdx.x >> 3;
    const int tid  = threadIdx.x;
    const int wave = tid >> 6;
    const int lane = tid & 63;
    const int quad = lane >> 4;
    const int l16  = lane & 15;
    const int dir  = wave & 1;
    const int pair = (wave >> 1) & 1;
    const int ks   = wave >> 2;
    const int q0   = qt * 64 + pair * 32;

    const size_t plane = (size_t)TT * CC;
    // All hot-loop loads: base + chunk*512 + lane*8 (ushorts) = contiguous 1KB/instr.
    const ushort* Qp = kt + (size_t)((dir == 0 ? 0 : NB) + b) * plane + (size_t)lane * 8;
    const ushort* Kp = kt + (size_t)((dir == 0 ? NB : 0) + b) * plane + (size_t)lane * 8;
    const ushort* Vp = vt + (size_t)((dir == 0 ? NB : 0) + b) * plane + (size_t)lane * 8;

    // pbuf[wave][par][rb][q=16][tok 64 + pad]: parity-split so S(j+1) writes and
    // PV(j) reads touch different regions -> DS queue no longer serializes them.
    __shared__ __align__(16) ushort pbuf[8][2][2][16][72];  // 72 KB
    __shared__ float lpx[8][2][16];                         // 1 KB
    f32a* xbuf = (f32a*)&pbuf[0][0][0][0][0];               // 16 KB overlay, post-loop

    // Q b-frags = kt chunks (qt, mt = pair*2 + rb, ch), pre-scaled.
    s16x8 qf[2][2];
#pragma unroll
    for (int rb = 0; rb < 2; ++rb)
#pragma unroll
        for (int ch = 0; ch < 2; ++ch)
            qf[rb][ch] = load_frag(Qp + (((size_t)qt * 4 + pair * 2 + rb) * 2 + ch) * 512);

    f32x4 accO[2][4];  // O^T partial: row=c=quad*4+r (+ct*16), col=q=l16 (+rb*16)
#pragma unroll
    for (int rb = 0; rb < 2; ++rb)
#pragma unroll
        for (int ct = 0; ct < 4; ++ct) accO[rb][ct] = (f32x4){0.f, 0.f, 0.f, 0.f};
    float lp[2] = {0.f, 0.f};

    // Named registers only (R14/R15 lesson: arrays spill under pressure).
    s16x8 kA0, kA1, kA2, kA3, kA4, kA5, kA6, kA7;   // K set A (even j)
    s16x8 kB0, kB1, kB2, kB3, kB4, kB5, kB6, kB7;   // K set B (odd j)
    s16x8 vA0, vA1, vA2, vA3, vA4, vA5, vA6, vA7;   // V set A (even j)
    s16x8 vB0, vB1, vB2, vB3, vB4, vB5, vB6, vB7;   // V set B (odd j)

    auto loadKA = [&](int j) {
        const ushort* p = Kp + (size_t)(ks * 32 + j) * 4096;
        kA0 = load_frag(p);          kA1 = load_frag(p + 512);
        kA2 = load_frag(p + 1024);   kA3 = load_frag(p + 1536);
        kA4 = load_frag(p + 2048);   kA5 = load_frag(p + 2560);
        kA6 = load_frag(p + 3072);   kA7 = load_frag(p + 3584);
    };
    auto loadKB = [&](int j) {
        const ushort* p = Kp + (size_t)(ks * 32 + j) * 4096;
        kB0 = load_frag(p);          kB1 = load_frag(p + 512);
        kB2 = load_frag(p + 1024);   kB3 = load_frag(p + 1536);
        kB4 = load_frag(p + 2048);   kB5 = load_frag(p + 2560);
        kB6 = load_frag(p + 3072);   kB7 = load_frag(p + 3584);
    };
    auto loadVA = [&](int j) {
        const ushort* p = Vp + (size_t)(ks * 32 + j) * 4096;
        vA0 = load_frag(p);          vA1 = load_frag(p + 512);
        vA2 = load_frag(p + 1024);   vA3 = load_frag(p + 1536);
        vA4 = load_frag(p + 2048);   vA5 = load_frag(p + 2560);
        vA6 = load_frag(p + 3072);   vA7 = load_frag(p + 3584);
    };
    auto loadVB = [&](int j) {
        const ushort* p = Vp + (size_t)(ks * 32 + j) * 4096;
        vB0 = load_frag(p);          vB1 = load_frag(p + 512);
        vB2 = load_frag(p + 1024);   vB3 = load_frag(p + 1536);
        vB4 = load_frag(p + 2048);   vB5 = load_frag(p + 2560);
        vB6 = load_frag(p + 3072);   vB7 = load_frag(p + 3584);
    };

    // One mt-slice of S^T into parity region par:
    // D[row=tok=quad*4+r (+mt*16)][col=q=l16] -> b64 P write.
    auto SmT = [&](s16x8 kc0, s16x8 kc1, int mt, int par) {
#pragma unroll
        for (int rb = 0; rb < 2; ++rb) {
            f32x4 s = (f32x4){0.f, 0.f, 0.f, 0.f};
            s = __builtin_amdgcn_mfma_f32_16x16x32_bf16(kc0, qf[rb][0], s, 0, 0, 0);
            s = __builtin_amdgcn_mfma_f32_16x16x32_bf16(kc1, qf[rb][1], s, 0, 0, 0);
            float p0 = __builtin_amdgcn_exp2f(s[0]);
            float p1 = __builtin_amdgcn_exp2f(s[1]);
            float p2 = __builtin_amdgcn_exp2f(s[2]);
            float p3 = __builtin_amdgcn_exp2f(s[3]);
            lp[rb] += (p0 + p1) + (p2 + p3);
            u32x2a w;
            w[0] = pack2(p0, p1);
            w[1] = pack2(p2, p3);
            *(u32x2a*)&pbuf[wave][par][rb][l16][mt * 16 + quad * 4] = w;
        }
    };
    // PV from parity region par with V set A (even j) / B (odd j).
    auto PVA = [&]() {
        s16x8 pf0a = load_frag(&pbuf[wave][0][0][l16][quad * 8]);
        s16x8 pf1a = load_frag(&pbuf[wave][0][1][l16][quad * 8]);
        accO[0][0] = __builtin_amdgcn_mfma_f32_16x16x32_bf16(vA0, pf0a, accO[0][0], 0, 0, 0);
        accO[1][0] = __builtin_amdgcn_mfma_f32_16x16x32_bf16(vA0, pf1a, accO[1][0], 0, 0, 0);
        accO[0][1] = __builtin_amdgcn_mfma_f32_16x16x32_bf16(vA1, pf0a, accO[0][1], 0, 0, 0);
        accO[1][1] = __builtin_amdgcn_mfma_f32_16x16x32_bf16(vA1, pf1a, accO[1][1], 0, 0, 0);
        accO[0][2] = __builtin_amdgcn_mfma_f32_16x16x32_bf16(vA2, pf0a, accO[0][2], 0, 0, 0);
        accO[1][2] = __builtin_amdgcn_mfma_f32_16x16x32_bf16(vA2, pf1a, accO[1][2], 0, 0, 0);
        accO[0][3] = __builtin_amdgcn_mfma_f32_16x16x32_bf16(vA3, pf0a, accO[0][3], 0, 0, 0);
        accO[1][3] = __builtin_amdgcn_mfma_f32_16x16x32_bf16(vA3, pf1a, accO[1][3], 0, 0, 0);
        s16x8 pf0b = load_frag(&pbuf[wave][0][0][l16][32 + quad * 8]);
        s16x8 pf1b = load_frag(&pbuf[wave][0][1][l16][32 + quad * 8]);
        accO[0][0] = __builtin_amdgcn_mfma_f32_16x16x32_bf16(vA4, pf0b, accO[0][0], 0, 0, 0);
        accO[1][0] = __builtin_amdgcn_mfma_f32_16x16x32_bf16(vA4, pf1b, accO[1][0], 0, 0, 0);
        accO[0][1] = __builtin_amdgcn_mfma_f32_16x16x32_bf16(vA5, pf0b, accO[0][1], 0, 0, 0);
        accO[1][1] = __builtin_amdgcn_mfma_f32_16x16x32_bf16(vA5, pf1b, accO[1][1], 0, 0, 0);
        accO[0][2] = __builtin_amdgcn_mfma_f32_16x16x32_bf16(vA6, pf0b, accO[0][2], 0, 0, 0);
        accO[1][2] = __builtin_amdgcn_mfma_f32_16x16x32_bf16(vA6, pf1b, accO[1][2], 0, 0, 0);
        accO[0][3] = __builtin_amdgcn_mfma_f32_16x16x32_bf16(vA7, pf0b, accO[0][3], 0, 0, 0);
        accO[1][3] = __builtin_amdgcn_mfma_f32_16x16x32_bf16(vA7, pf1b, accO[1][3], 0, 0, 0);
    };
    auto PVB = [&]() {
        s16x8 pf0a = load_frag(&pbuf[wave][1][0][l16][quad * 8]);
        s16x8 pf1a = load_frag(&pbuf[wave][1][1][l16][quad * 8]);
        accO[0][0] = __builtin_amdgcn_mfma_f32_16x16x32_bf16(vB0, pf0a, accO[0][0], 0, 0, 0);
        accO[1][0] = __builtin_amdgcn_mfma_f32_16x16x32_bf16(vB0, pf1a, accO[1][0], 0, 0, 0);
        accO[0][1] = __builtin_amdgcn_mfma_f32_16x16x32_bf16(vB1, pf0a, accO[0][1], 0, 0, 0);
        accO[1][1] = __builtin_amdgcn_mfma_f32_16x16x32_bf16(vB1, pf1a, accO[1][1], 0, 0, 0);
        accO[0][2] = __builtin_amdgcn_mfma_f32_16x16x32_bf16(vB2, pf0a, accO[0][2], 0, 0, 0);
        accO[1][2] = __builtin_amdgcn_mfma_f32_16x16x32_bf16(vB2, pf1a, accO[1][2], 0, 0, 0);
        accO[0][3] = __builtin_amdgcn_mfma_f32_16x16x32_bf16(vB3, pf0a, accO[0][3], 0, 0, 0);
        accO[1][3] = __builtin_amdgcn_mfma_f32_16x16x32_bf16(vB3, pf1a, accO[1][3], 0, 0, 0);
        s16x8 pf0b = load_frag(&pbuf[wave][1][0][l16][32 + quad * 8]);
        s16x8 pf1b = load_frag(&pbuf[wave][1][1][l16][32 + quad * 8]);
        accO[0][0] = __builtin_amdgcn_mfma_f32_16x16x32_bf16(vB4, pf0b, accO[0][0], 0, 0, 0);
        accO[1][0] = __builtin_amdgcn_mfma_f32_16x16x32_bf16(vB4, pf1b, accO[1][0], 0, 0, 0);
        accO[0][1] = __builtin_amdgcn_mfma_f32_16x16x32_bf16(vB5, pf0b, accO[0][1], 0, 0, 0);
        accO[1][1] = __builtin_amdgcn_mfma_f32_16x16x32_bf16(vB5, pf1b, accO[1][1], 0, 0, 0);
        accO[0][2] = __builtin_amdgcn_mfma_f32_16x16x32_bf16(vB6, pf0b, accO[0][2], 0, 0, 0);
        accO[1][2] = __builtin_amdgcn_mfma_f32_16x16x32_bf16(vB6, pf1b, accO[1][2], 0, 0, 0);
        accO[0][3] = __builtin_amdgcn_mfma_f32_16x16x32_bf16(vB7, pf0b, accO[0][3], 0, 0, 0);
        accO[1][3] = __builtin_amdgcn_mfma_f32_16x16x32_bf16(vB7, pf1b, accO[1][3], 0, 0, 0);
    };

    // Barrier-free parity pipeline, unroll 2. Per iter (j even):
    //   loadKB(j+1) -> S(kA)->par0 -> loadVB(j+1) -> S(kB)->par1 [indep of PV]
    //   -> loadKA(j+2) -> PV(j){vA,par0: written 1 phase ago} -> loadVA(j+2)
    //   -> PV(j+1){vB,par1}.
    // Every consumer's input is >=1 full phase old; the DS in-order queue no
    // longer chains S(j+1) writes behind PV(j) reads (different parity region).
    loadKA(0);
    loadVA(0);
#pragma unroll 1
    for (int j = 0; j < 32; j += 2) {
        loadKB(j + 1);
        SmT(kA0, kA1, 0, 0); SmT(kA2, kA3, 1, 0); SmT(kA4, kA5, 2, 0); SmT(kA6, kA7, 3, 0);
        loadVB(j + 1);
        SmT(kB0, kB1, 0, 1); SmT(kB2, kB3, 1, 1); SmT(kB4, kB5, 2, 1); SmT(kB6, kB7, 3, 1);
        if (j + 2 < 32) loadKA(j + 2);
        PVA();                           // PV(j)
        if (j + 2 < 32) loadVA(j + 2);
        PVB();                           // PV(j+1)
    }

    // Denominator: quads hold disjoint token subsets for col q=l16.
    float inv[2];
#pragma unroll
    for (int rb = 0; rb < 2; ++rb) {
        float l = lp[rb];
        l += __shfl_xor(l, 16);
        l += __shfl_xor(l, 32);
        lp[rb] = l;
        if (lane < 16) lpx[wave][rb][l16] = l;
    }
    __syncthreads();  // joins ALL waves after their last pbuf use ->
                      // xbuf overlay safe; lpx visible
#pragma unroll
    for (int rb = 0; rb < 2; ++rb)
        inv[rb] = __builtin_amdgcn_rcpf(lp[rb] + lpx[wave ^ 4][rb][l16]);

    // 4-phase merge over g = (ks,dir) into xbuf[pair]; g==0 stores.
    const int g = (ks << 1) | dir;
#pragma unroll 1
    for (int ph = 3; ph >= 1; --ph) {
        if (g == ph) {
#pragma unroll
            for (int rb = 0; rb < 2; ++rb)
#pragma unroll
                for (int ct = 0; ct < 4; ++ct)
#pragma unroll
                    for (int r = 0; r < 4; ++r) {
                        const int slot = (pair * 32 + rb * 16 + ct * 4 + r) * 64 + lane;
                        float v = accO[rb][ct][r] * inv[rb];
                        if (ph == 3) xbuf[slot] = v;
                        else xbuf[slot] += v;
                    }
        }
        __syncthreads();
    }
    if (g == 0) {
        float* ob = out + (size_t)b * plane;
#pragma unroll
        for (int rb = 0; rb < 2; ++rb)
#pragma unroll
            for (int ct = 0; ct < 4; ++ct)
#pragma unroll
                for (int r = 0; r < 4; ++r) {
                    float v = accO[rb][ct][r] * inv[rb] +
                              xbuf[(pair * 32 + rb * 16 + ct * 4 + r) * 64 + lane];
                    // out[c = ct*16+quad*4+r][t = q0+rb*16+l16]: coalesced over l16
                    ob[(size_t)(ct * 16 + quad * 4 + r) * TT + q0 + rb * 16 + l16] = v;
                }
    }
}

extern "C" void kernel_launch(void* const* d_in, const int* in_sizes, int n_in,
                              void* d_out, int out_size, void* d_ws, size_t ws_size,
                              hipStream_t stream) {
    const float* x1 = (const float*)d_in[0];
    const float* x2 = (const float*)d_in[1];
    ushort* kt = (ushort*)d_ws;                              // 8 MB frag-packed K/Q
    ushort* vt = (ushort*)d_ws + (size_t)2 * NB * TT * CC;   // 8 MB frag-packed V

    hipLaunchKernelGGL(prep_k, dim3(TT / 64, NB, 2), dim3(256), 0, stream, x1, x2, kt, vt);
    hipLaunchKernelGGL(attn_fused_k, dim3(64 * NB), dim3(512), 0, stream,
                       kt, vt, (float*)d_out);
}